// Round 1
// 194.092 us; speedup vs baseline: 1.0504x; 1.0504x over previous
//
#include <hip/hip_runtime.h>
#include <hip/hip_bf16.h>

#define B_ 4
#define C_ 32
#define H_ 256
#define W_ 256
#define S_ 65536      // H*W
#define NP_ 9
#define OC_ 288       // C_*NP_
#define PR 258        // padded rows
#define PWN 264       // padded width stride (NHWC)

using bf16 = __hip_bfloat16;
typedef __attribute__((ext_vector_type(8)))  short  short8;
typedef __attribute__((ext_vector_type(4)))  short  short4_t;
typedef __attribute__((ext_vector_type(16))) float  f32x16;

__device__ __forceinline__ float b2f(short s) {
    return __uint_as_float(((unsigned)(unsigned short)s) << 16);
}

// ---------------- prep bodies ----------------
template<int IC, int OC>
__device__ __forceinline__ void prepA_body(int fid, const float* __restrict__ w,
                                           bf16* __restrict__ apk)
{
    constexpr int NK = 9 * IC / 16;
    int tile = fid >> 9;
    int l = (fid >> 3) & 63;
    int j = fid & 7;
    int mt = tile / NK;
    int ks = tile - mt * NK;
    int q = l >> 5;
    int oc = mt * 32 + (l & 31);
    int k = ks * 16 + q * 8 + j;
    int tap = k / IC;
    int ic = k - tap * IC;
    apk[fid] = __float2bfloat16(w[((oc * IC + ic) * 3 + tap / 3) * 3 + tap % 3]);
}

template<int G>
__device__ __forceinline__ void zerob_body(int b, int p, uint4* __restrict__ buf)
{
    int gran;
    if (p < 2 * PWN * G) {
        int row = (p < PWN * G) ? 0 : 257;
        int rem = p % (PWN * G);
        gran = row * PWN * G + rem;
    } else {
        int p2 = p - 2 * PWN * G;
        int col = (p2 < 256 * G) ? 0 : 257;
        int rem = p2 % (256 * G);
        int r = rem / G + 1;
        int icg = rem - (rem / G) * G;
        gran = (r * PWN + col) * G + icg;
    }
    buf[(size_t)b * PR * PWN * G + gran] = uint4{0, 0, 0, 0};
}

// ---------------- K_prep: weight packs + tA border zero + xk/xv border-row zero ----
// New section [82176, 106752): zero the shifted-store border rows of xk/xv
// (row 0 for di=-1 plane groups pp 0..2 = ch 0..95; row 255 for di=+1 groups
// pp 6..8 = ch 192..287), both batches of the 2-batch buffer. conv1x1s never
// writes them, so one-time zeroing persists across both bp iterations.
__global__ __launch_bounds__(256) void k_prep(
    const float* __restrict__ wk, const float* __restrict__ wv,
    const float* __restrict__ wq,
    const float* __restrict__ w1, const float* __restrict__ w2,
    const float* __restrict__ w3,
    bf16* __restrict__ apk0, bf16* __restrict__ apk1,
    bf16* __restrict__ apk2, bf16* __restrict__ apk3,
    uint4* __restrict__ tA,
    bf16* __restrict__ xk, bf16* __restrict__ xv)
{
    int idx = blockIdx.x * 256 + threadIdx.x;
    if (idx < 19456) {
        int j    = idx & 7;
        int lane = (idx >> 3) & 63;
        int ks   = (idx >> 9) & 1;
        int mt   = idx >> 10;
        int oc = lane & 31;
        int ic = ks * 16 + (lane >> 5) * 8 + j;
        const float* w; int ocg;
        if (mt < 9)       { w = wk; ocg = mt * 32 + oc; }
        else if (mt < 18) { w = wv; ocg = (mt - 9) * 32 + oc; }
        else              { w = wq; ocg = oc; }
        apk0[idx] = __float2bfloat16(w[ocg * C_ + ic]);
    } else if (idx < 28672) {
        prepA_body<32, 32>(idx - 19456, w1, apk1);
    } else if (idx < 47104) {
        prepA_body<32, 64>(idx - 28672, w2, apk2);
    } else if (idx < 65536) {
        prepA_body<64, 32>(idx - 47104, w3, apk3);
    } else if (idx < 82176) {
        int i5 = idx - 65536;
        zerob_body<4>(i5 / 4160, i5 % 4160, tA);
    } else if (idx < 106752) {
        int i6 = idx - 82176;            // [0, 24576) granules of 16B
        int gr = i6 & 31;                // granule within 512B row
        int pr = i6 >> 5;                // [0, 768) plane-rows
        int kv  = pr >= 384;
        int r2  = pr - (kv ? 384 : 0);
        int bb  = r2 >= 192;
        int r3  = r2 - (bb ? 192 : 0);
        int top = r3 >= 96;
        int cc  = r3 - (top ? 96 : 0);
        int ch  = top ? 192 + cc : cc;
        int row = top ? 255 : 0;
        bf16* dst = (kv ? xv : xk) + (size_t)bb * ((size_t)OC_ * S_)
                  + (size_t)ch * S_ + row * 256 + gr * 8;
        *reinterpret_cast<uint4*>(dst) = uint4{0, 0, 0, 0};
    }
}

// ---------------- shifted-store helper: extract cols [g*8+dj, g*8+8+dj) ----------
// rowb points at LDS row base; col c lives at rowb[8+c]; pads [0..7] and
// [264..271] hold zeros, so border shifts pull in zeros automatically.
__device__ __forceinline__ short8 shifted(const bf16* __restrict__ rowb, int g, int dj)
{
    union U { short8 s; unsigned u[4]; };
    if (dj == 0)
        return *reinterpret_cast<const short8*>(rowb + 8 + g * 8);
    U a, b, o;
    if (dj == 1) {
        a.s = *reinterpret_cast<const short8*>(rowb + 8 + g * 8);
        b.s = *reinterpret_cast<const short8*>(rowb + 16 + g * 8);
        unsigned win[5] = {a.u[0], a.u[1], a.u[2], a.u[3], b.u[0]};
#pragma unroll
        for (int i = 0; i < 4; ++i) o.u[i] = (win[i] >> 16) | (win[i + 1] << 16);
    } else {
        a.s = *reinterpret_cast<const short8*>(rowb + g * 8);
        b.s = *reinterpret_cast<const short8*>(rowb + 8 + g * 8);
        unsigned win[5] = {a.u[3], b.u[0], b.u[1], b.u[2], b.u[3]};
#pragma unroll
        for (int i = 0; i < 4; ++i) o.u[i] = (win[i] >> 16) | (win[i + 1] << 16);
    }
    return o.s;
}

// ---------------- K0: 1x1 convs via MFMA, SHIFTED planar store ---------------------
// Full-row blocks: 512 threads = 8 waves x 32 px cover one 256-px row, so the
// dj=+-1 column shift has its halo entirely in-block (LDS zero pads at row ends).
// K/V plane group pp stores to row r-di with cols shifted by dj => attention
// reads become single aligned flat granules. Q (mt=18) stays unshifted planar.
__global__ __launch_bounds__(512) void k_conv1x1s(
    const float* __restrict__ x,        // batch-pair base, [2][32][65536] fp32
    const bf16* __restrict__ apk,       // packed weights [19][2][64][8]
    const float* __restrict__ bk, const float* __restrict__ bv,
    const float* __restrict__ bq,
    bf16* __restrict__ xk, bf16* __restrict__ xv, bf16* __restrict__ xq)
{
    constexpr int RS = 280;             // shorts per LDS row: 8 pad | 256 | 8 pad | 8 spare
    __shared__ bf16 lbuf[2][32][RS];    // double-buffered; rows 560B (16B-aligned)

    int bh = blockIdx.x >> 8;           // batch within pair
    int r  = blockIdx.x & 255;          // output row
    int tid  = threadIdx.x;
    int wvi  = tid >> 6;                // 0..7
    int lane = tid & 63;
    int col  = lane & 31, q = lane >> 5;

    const float* xb = x + (size_t)bh * (C_ * S_);
    bf16* xkb = xk + (size_t)bh * ((size_t)OC_ * S_);
    bf16* xvb = xv + (size_t)bh * ((size_t)OC_ * S_);
    bf16* xqb = xq + (size_t)bh * (32 * S_);

    // zero the shift pads of both buffers (cols -8..-1 and 256..263)
    if (tid < 128) {
        int b = tid >> 6, ch = (tid >> 1) & 31, hi = tid & 1;
        *reinterpret_cast<uint4*>(&lbuf[b][ch][hi ? 264 : 0]) = uint4{0, 0, 0, 0};
    }

    int pix = r * 256 + wvi * 32 + col;
    short8 bfrag[2];
#pragma unroll
    for (int kk = 0; kk < 2; ++kk)
#pragma unroll
        for (int j = 0; j < 8; ++j) {
            bf16 h = __float2bfloat16(xb[(size_t)(kk * 16 + q * 8 + j) * S_ + pix]);
            bfrag[kk][j] = *reinterpret_cast<short*>(&h);
        }

    const short8* apkv = reinterpret_cast<const short8*>(apk);

    int sch = tid >> 4;                 // store-phase channel 0..31
    int sgk = tid & 15;                 // store-phase granule base

    for (int mt = 0; mt < 19; ++mt) {
        int buf = mt & 1;
        f32x16 acc = {};
        acc = __builtin_amdgcn_mfma_f32_32x32x16_bf16(bfrag[0], apkv[(mt * 2 + 0) * 64 + lane], acc, 0, 0, 0);
        acc = __builtin_amdgcn_mfma_f32_32x32x16_bf16(bfrag[1], apkv[(mt * 2 + 1) * 64 + lane], acc, 0, 0, 0);
        float bbv = (mt < 9) ? bk[mt * 32 + col]
                  : (mt < 18) ? bv[(mt - 9) * 32 + col]
                  : bq[col];
#pragma unroll
        for (int g4 = 0; g4 < 4; ++g4) {
            short4_t sv;
#pragma unroll
            for (int j = 0; j < 4; ++j) {
                bf16 hb = __float2bfloat16(acc[g4 * 4 + j] + bbv);
                sv[j] = *reinterpret_cast<short*>(&hb);
            }
            *reinterpret_cast<short4_t*>(&lbuf[buf][col][8 + wvi * 32 + 8 * g4 + 4 * q]) = sv;
        }
        __syncthreads();
        int pp = (mt < 9) ? mt : (mt < 18) ? mt - 9 : 4;   // Q => pp=4 (no shift)
        int di = pp / 3 - 1;
        int dj = pp - (pp / 3) * 3 - 1;
        int rp = r - di;
        bf16* ob = (mt < 9)  ? xkb + (size_t)(mt * 32) * S_
                 : (mt < 18) ? xvb + (size_t)((mt - 9) * 32) * S_
                 :             xqb;
        if ((unsigned)rp < 256u) {                         // block-uniform
            const bf16* rowb = &lbuf[buf][sch][0];
            bf16* orow = ob + (size_t)sch * S_ + rp * 256;
#pragma unroll
            for (int gg = 0; gg < 2; ++gg) {
                int gr = sgk + gg * 16;
                short8 v = shifted(rowb, gr, dj);
                *reinterpret_cast<short8*>(orow + gr * 8) = v;
            }
        }
    }
}

// ---------------- K1: attention on pre-shifted K/V — flat aligned granule loads ----
// score(tl,hh,p) needs exactly xk_s[tl*288 + p*32 + hh*8 .. +8): one aligned 16B
// load; the 9 p-loads of a 4-lane group tile a contiguous 576B span. No funnel,
// no validity masks (borders are zero in storage). Score mask (m's own flat-view
// decomposition) kept verbatim.
__global__ __launch_bounds__(256, 4) void k_attn3(
    const bf16* __restrict__ xk, const bf16* __restrict__ xv,
    const bf16* __restrict__ xq, bf16* __restrict__ att)
{
    unsigned g = blockIdx.x * 256u + threadIdx.x;   // [0, 2*S*4)
    unsigned t = g >> 2;                            // [0, 2*S)
    int hh = g & 3;
    unsigned bb = t >> 16;
    unsigned tl = t & 65535;

    const bf16* xkb = xk + (size_t)bb * ((size_t)OC_ * S_);
    const bf16* xvb = xv + (size_t)bb * ((size_t)OC_ * S_);
    size_t f0 = (size_t)tl * 288 + hh * 8;

    float qv[8];
    {
        short8 qg = *reinterpret_cast<const short8*>(
            xq + (size_t)bb * (32 * S_) + (size_t)tl * 32 + hh * 8);
#pragma unroll
        for (int j = 0; j < 8; ++j) qv[j] = b2f(qg[j]);
    }

    // issue all K and V loads up front (independent; hides HBM latency)
    short8 kg[NP_], vg[NP_];
#pragma unroll
    for (int p = 0; p < NP_; ++p)
        kg[p] = *reinterpret_cast<const short8*>(xkb + f0 + p * 32);
#pragma unroll
    for (int p = 0; p < NP_; ++p)
        vg[p] = *reinterpret_cast<const short8*>(xvb + f0 + p * 32);

    // ---- scores ----
    float sc[NP_];
#pragma unroll
    for (int p = 0; p < NP_; ++p) {
        float dot = 0.f;
#pragma unroll
        for (int j = 0; j < 8; ++j) dot += qv[j] * b2f(kg[p][j]);
        dot += __shfl_xor(dot, 1);
        dot += __shfl_xor(dot, 2);
        // mask: decompose tl*9+p in (p'', s'') coords (m's own flat view)
        int rm = tl * 9 + p;
        int pm = rm >> 16, sm = rm & (S_ - 1);
        int dim = pm / 3 - 1;
        int djm = pm - (pm / 3) * 3 - 1;
        int hm = sm >> 8, wm = sm & 255;
        bool mval = ((unsigned)(hm + dim) < 256u) && ((unsigned)(wm + djm) < 256u);
        sc[p] = mval ? dot * 0.125f : 0.f;
    }

    // ---- softmax ----
    float mx = sc[0];
#pragma unroll
    for (int p = 1; p < NP_; ++p) mx = fmaxf(mx, sc[p]);
    float wgt[NP_];
    float sum = 0.f;
#pragma unroll
    for (int p = 0; p < NP_; ++p) { wgt[p] = __expf(sc[p] - mx); sum += wgt[p]; }
    float inv = 1.f / sum;

    // ---- weighted V accumulate ----
    float acc[8];
#pragma unroll
    for (int j = 0; j < 8; ++j) acc[j] = 0.f;
#pragma unroll
    for (int p = 0; p < NP_; ++p) {
        float wp = wgt[p];
#pragma unroll
        for (int j = 0; j < 8; ++j) acc[j] += wp * b2f(vg[p][j]);
    }

    bf16* dst = att + (size_t)bb * (32 * S_) + (size_t)tl * 32 + hh * 8;
    short8 sv;
#pragma unroll
    for (int j = 0; j < 8; ++j) {
        bf16 hb = __float2bfloat16(acc[j] * inv);
        sv[j] = *reinterpret_cast<short*>(&hb);
    }
    *reinterpret_cast<short8*>(dst) = sv;
}

// ---------------- K2: repack att -> tA (NHWC) + zero t1/t2 borders, one launch ----
__global__ __launch_bounds__(256) void k_repzero(
    const bf16* __restrict__ att, bf16* __restrict__ tA,
    uint4* __restrict__ t1, uint4* __restrict__ t2)
{
    int idx = blockIdx.x * 256 + threadIdx.x;
    if (idx < 1048576) {                          // B*S*4 repack threads
        int icg = idx & 3;
        int ps  = idx >> 2;
        int b = ps >> 16;
        int s = ps & 65535;
        const bf16* src = att + (size_t)b * (32 * S_) + icg * 8 * S_ + s;
        short8 v;
#pragma unroll
        for (int j = 0; j < 8; ++j)
            v[j] = *reinterpret_cast<const short*>(src + (size_t)j * S_);
        int row = (s >> 8) + 1, colp = (s & 255) + 1;
        *reinterpret_cast<short8*>(tA + ((size_t)((b * PR + row) * PWN + colp)) * 32 + icg * 8) = v;
    } else {
        int i2 = idx - 1048576;
        if (i2 < 16640) {
            zerob_body<4>(i2 / 4160, i2 % 4160, t1);
        } else if (i2 < 49920) {
            int i3 = i2 - 16640;
            zerob_body<8>(i3 / 8320, i3 % 8320, t2);
        }
    }
}

// ---------------- K4: 3x3 conv + ReLU via MFMA, one-shot LDS staging ----------------
template<int IC, int OC, bool NCHW_OUT>
__global__ __launch_bounds__(256) void k_conv3s(
    const bf16* __restrict__ in,    // NHWC bf16 padded [B][PR][PWN][IC]
    const bf16* __restrict__ apk,
    const float* __restrict__ bs,
    void* __restrict__ outv)
{
    constexpr int G    = IC / 8;         // 16B granules per pixel
    constexpr int M    = OC / 32;
    constexpr int KPT  = IC / 16;
    constexpr int NK   = 9 * KPT;
    constexpr int NT   = 2;
    constexpr int ROWP = 66;
    constexpr int ROWG = ROWP * G;
    constexpr int TOTG = 6 * ROWG;

    __shared__ uint4 smem[TOTG];

    // XCD-aware bijective swizzle over 1024 wgs
    int wg   = blockIdx.x;
    int orig = (wg & 7) * 128 + (wg >> 3);
    int b   = orig >> 8;
    int rem = orig & 255;
    int h0  = (rem >> 2) << 2;           // output row group [h0, h0+4)
    int w0  = (rem & 3) * 64;            // output col group [w0, w0+64)

    int tid = threadIdx.x;

    // ---- stage 6 x 66 px into LDS (XOR-swizzled 16B granules) ----
    {
        const uint4* src = reinterpret_cast<const uint4*>(in);
#pragma unroll
        for (int i = 0; i < (TOTG + 255) / 256; ++i) {
            int idx = tid + i * 256;
            if (idx < TOTG) {
                int dr = idx / ROWG;
                int r2 = idx - dr * ROWG;          // px*G + g
                uint4 v = src[((size_t)(b * PR + h0 + dr) * PWN + w0) * G + r2];
                int px = r2 >> ((G == 4) ? 2 : 3);
                int sw = (G == 4) ? ((px ^ (px >> 2)) & 3) : (px & 7);
                smem[dr * ROWG + (r2 & ~(G - 1)) + ((r2 ^ sw) & (G - 1))] = v;
            }
        }
    }
    __syncthreads();

    int lane = tid & 63;
    int wid  = tid >> 6;
    int col  = lane & 31, q = lane >> 5;
    int h    = h0 + wid;                 // this wave's output row

    const short8* apkv = reinterpret_cast<const short8*>(apk);

    f32x16 acc[NT][M];
#pragma unroll
    for (int nt = 0; nt < NT; ++nt)
#pragma unroll
        for (int mt = 0; mt < M; ++mt) acc[nt][mt] = (f32x16){};

#pragma unroll
    for (int tap = 0; tap < 9; ++tap) {
        int dr = tap / 3 + wid;          // input row within the 6 staged (wave offset)
        int dj = tap % 3;
#pragma unroll
        for (int icq = 0; icq < KPT; ++icq) {
            short8 bfr[NT];
#pragma unroll
            for (int nt = 0; nt < NT; ++nt) {
                int px = nt * 32 + col + dj;
                int sw = (G == 4) ? ((px ^ (px >> 2)) & 3) : (px & 7);
                bfr[nt] = *reinterpret_cast<const short8*>(
                    &smem[dr * ROWG + px * G + ((icq * 2 + q) ^ sw)]);
            }
#pragma unroll
            for (int mt = 0; mt < M; ++mt) {
                short8 afr = apkv[(mt * NK + tap * KPT + icq) * 64 + lane];
#pragma unroll
                for (int nt = 0; nt < NT; ++nt)
                    acc[nt][mt] = __builtin_amdgcn_mfma_f32_32x32x16_bf16(
                        afr, bfr[nt], acc[nt][mt], 0, 0, 0);
            }
        }
    }

    // ---- epilogue: bias + relu + store ----
#pragma unroll
    for (int nt = 0; nt < NT; ++nt) {
        int wout = w0 + nt * 32 + col;             // [0,256)
#pragma unroll
        for (int mt = 0; mt < M; ++mt) {
            if (NCHW_OUT) {
                float* out = (float*)outv;
#pragma unroll
                for (int r = 0; r < 16; ++r) {
                    int oc = mt * 32 + (r & 3) + 8 * (r >> 2) + 4 * q;
                    out[(size_t)((b * OC + oc) * H_ + h) * W_ + wout] =
                        fmaxf(acc[nt][mt][r] + bs[oc], 0.f);
                }
            } else {
                bf16* out = (bf16*)outv;
                size_t base = (size_t)((b * PR + h + 1) * PWN + wout + 1) * OC + mt * 32 + 4 * q;
#pragma unroll
                for (int g4 = 0; g4 < 4; ++g4) {
                    short4_t sv;
#pragma unroll
                    for (int r4 = 0; r4 < 4; ++r4) {
                        int oc = mt * 32 + 8 * g4 + 4 * q + r4;
                        bf16 hh = __float2bfloat16(fmaxf(acc[nt][mt][g4 * 4 + r4] + bs[oc], 0.f));
                        sv[r4] = *reinterpret_cast<short*>(&hh);
                    }
                    *reinterpret_cast<short4_t*>(out + base + 8 * g4) = sv;
                }
            }
        }
    }
}

extern "C" void kernel_launch(void* const* d_in, const int* in_sizes, int n_in,
                              void* d_out, int out_size, void* d_ws, size_t ws_size,
                              hipStream_t stream)
{
    const float* x  = (const float*)d_in[0];
    const float* wk = (const float*)d_in[1];
    const float* bk = (const float*)d_in[2];
    const float* wv = (const float*)d_in[3];
    const float* bv = (const float*)d_in[4];
    const float* wq = (const float*)d_in[5];
    const float* bq = (const float*)d_in[6];
    const float* w1 = (const float*)d_in[7];
    const float* b1 = (const float*)d_in[8];
    const float* w2 = (const float*)d_in[9];
    const float* b2 = (const float*)d_in[10];
    const float* w3 = (const float*)d_in[11];
    const float* b3 = (const float*)d_in[12];
    float* out = (float*)d_out;
    char* ws = (char*)d_ws;

    // ---- workspace layout (2-batch K/V + guard; peak ~177 MB < 256 MiB) ----
    bf16*  xk    = (bf16*)(ws + 32);               // 2-batch K (shifted): 75,497,472 B
    bf16*  xv    = xk + 2 * (size_t)OC_ * S_;      // 2-batch V (shifted): 75,497,472 B
    bf16*  xq    = xv + 2 * (size_t)OC_ * S_;      // 2-batch Q bf16: 8,388,608 B
    bf16*  tA    = (bf16*)(ws + 159383584);        // NHWC 32ch, 4 batches: 17,436,672
    bf16*  apk0  = (bf16*)(ws + 176820256);        // 38,912
    bf16*  apk1  = (bf16*)(ws + 176859168);        // 18,432
    bf16*  apk2  = (bf16*)(ws + 176877600);        // 36,864
    bf16*  apk3  = (bf16*)(ws + 176914464);        // 36,864 (end 176,951,328)
    // conv phase (alias dead xk region):
    bf16*  t1    = (bf16*)(ws);                    // NHWC 32ch: 0 .. 17,436,672
    bf16*  t2    = (bf16*)(ws + 17436672);         // NHWC 64ch: .. 52,310,016
    // attention output scratch: d_out region (dead until final conv)
    bf16*  attB  = (bf16*)d_out;

    // weight packs + tA border zeroing + xk/xv shifted-store border rows
    k_prep<<<417, 256, 0, stream>>>(wk, wv, wq, w1, w2, w3,
                                    apk0, apk1, apk2, apk3, (uint4*)tA, xk, xv);

    for (int bp = 0; bp < 2; ++bp) {
        k_conv1x1s<<<512, 512, 0, stream>>>(x + (size_t)bp * 2 * C_ * S_,
                                            apk0, bk, bv, bq, xk, xv, xq);
        k_attn3<<<2048, 256, 0, stream>>>(xk, xv, xq,
                                          attB + (size_t)bp * 2 * (32 * S_));
    }
    // repack planar bf16 (attB, flat-identity) -> NHWC bf16 padded tA,
    // plus zero borders of t1/t2 (xk region dead now)
    k_repzero<<<4291, 256, 0, stream>>>(attB, tA, (uint4*)t1, (uint4*)t2);

    k_conv3s<32, 32, false><<<1024, 256, 0, stream>>>(tA, apk1, b1, (void*)t1);
    k_conv3s<32, 64, false><<<1024, 256, 0, stream>>>(t1, apk2, b2, (void*)t2);
    k_conv3s<64, 32, true ><<<1024, 256, 0, stream>>>(t2, apk3, b3, (void*)out);
}

// Round 2
// 183.664 us; speedup vs baseline: 1.1101x; 1.0568x over previous
//
#include <hip/hip_runtime.h>
#include <hip/hip_bf16.h>

#define B_ 4
#define C_ 32
#define H_ 256
#define W_ 256
#define S_ 65536      // H*W
#define NP_ 9
#define OC_ 288       // C_*NP_
#define PR 258        // padded rows
#define PWN 264       // padded width stride (NHWC)

using bf16 = __hip_bfloat16;
typedef __attribute__((ext_vector_type(8)))  short  short8;
typedef __attribute__((ext_vector_type(4)))  short  short4_t;
typedef __attribute__((ext_vector_type(16))) float  f32x16;

__device__ __forceinline__ float b2f(short s) {
    return __uint_as_float(((unsigned)(unsigned short)s) << 16);
}

// ---------------- prep bodies ----------------
template<int IC, int OC>
__device__ __forceinline__ void prepA_body(int fid, const float* __restrict__ w,
                                           bf16* __restrict__ apk)
{
    constexpr int NK = 9 * IC / 16;
    int tile = fid >> 9;
    int l = (fid >> 3) & 63;
    int j = fid & 7;
    int mt = tile / NK;
    int ks = tile - mt * NK;
    int q = l >> 5;
    int oc = mt * 32 + (l & 31);
    int k = ks * 16 + q * 8 + j;
    int tap = k / IC;
    int ic = k - tap * IC;
    apk[fid] = __float2bfloat16(w[((oc * IC + ic) * 3 + tap / 3) * 3 + tap % 3]);
}

template<int G>
__device__ __forceinline__ void zerob_body(int b, int p, uint4* __restrict__ buf)
{
    int gran;
    if (p < 2 * PWN * G) {
        int row = (p < PWN * G) ? 0 : 257;
        int rem = p % (PWN * G);
        gran = row * PWN * G + rem;
    } else {
        int p2 = p - 2 * PWN * G;
        int col = (p2 < 256 * G) ? 0 : 257;
        int rem = p2 % (256 * G);
        int r = rem / G + 1;
        int icg = rem - (rem / G) * G;
        gran = (r * PWN + col) * G + icg;
    }
    buf[(size_t)b * PR * PWN * G + gran] = uint4{0, 0, 0, 0};
}

// ---------------- K_prep: weight packs + border zeroing of tA/t1/t2 ----------------
// t1/t2 no longer alias live K/V buffers (fused pipeline removed xk/xv), so their
// borders are zeroed once here; conv3s only writes interiors.
__global__ __launch_bounds__(256) void k_prep(
    const float* __restrict__ wk, const float* __restrict__ wv,
    const float* __restrict__ wq,
    const float* __restrict__ w1, const float* __restrict__ w2,
    const float* __restrict__ w3,
    bf16* __restrict__ apk0, bf16* __restrict__ apk1,
    bf16* __restrict__ apk2, bf16* __restrict__ apk3,
    uint4* __restrict__ tA, uint4* __restrict__ t1, uint4* __restrict__ t2)
{
    int idx = blockIdx.x * 256 + threadIdx.x;
    if (idx < 19456) {
        int j    = idx & 7;
        int lane = (idx >> 3) & 63;
        int ks   = (idx >> 9) & 1;
        int mt   = idx >> 10;
        int oc = lane & 31;
        int ic = ks * 16 + (lane >> 5) * 8 + j;
        const float* w; int ocg;
        if (mt < 9)       { w = wk; ocg = mt * 32 + oc; }
        else if (mt < 18) { w = wv; ocg = (mt - 9) * 32 + oc; }
        else              { w = wq; ocg = oc; }
        apk0[idx] = __float2bfloat16(w[ocg * C_ + ic]);
    } else if (idx < 28672) {
        prepA_body<32, 32>(idx - 19456, w1, apk1);
    } else if (idx < 47104) {
        prepA_body<32, 64>(idx - 28672, w2, apk2);
    } else if (idx < 65536) {
        prepA_body<64, 32>(idx - 47104, w3, apk3);
    } else if (idx < 82176) {
        int i5 = idx - 65536;
        zerob_body<4>(i5 / 4160, i5 % 4160, tA);
    } else if (idx < 98816) {
        int i6 = idx - 82176;
        zerob_body<4>(i6 / 4160, i6 % 4160, t1);
    } else if (idx < 132096) {
        int i7 = idx - 98816;
        zerob_body<8>(i7 / 8320, i7 % 8320, t2);
    }
}

// ---------------- K_q: 1x1 Q-conv via MFMA, planar bf16 out, all 4 batches --------
__global__ __launch_bounds__(256) void k_q(
    const float* __restrict__ x, const bf16* __restrict__ apk,
    const float* __restrict__ bq, bf16* __restrict__ xq)
{
    __shared__ bf16 lbuf[32][140];
    int bh  = blockIdx.x >> 9;          // batch 0..3
    int blk = blockIdx.x & 511;
    int pixw0 = blk << 7;
    int tid  = threadIdx.x;
    int wvi  = tid >> 6;
    int lane = tid & 63;
    int col  = lane & 31, q = lane >> 5;
    int pix  = pixw0 + wvi * 32 + col;

    const float* xb = x + (size_t)bh * (C_ * S_);
    bf16* xqb = xq + (size_t)bh * (32 * S_);

    short8 bfrag[2];
#pragma unroll
    for (int kk = 0; kk < 2; ++kk)
#pragma unroll
        for (int j = 0; j < 8; ++j) {
            bf16 h = __float2bfloat16(xb[(size_t)(kk * 16 + q * 8 + j) * S_ + pix]);
            bfrag[kk][j] = *reinterpret_cast<short*>(&h);
        }

    const short8* apkv = reinterpret_cast<const short8*>(apk);
    f32x16 acc = {};
    acc = __builtin_amdgcn_mfma_f32_32x32x16_bf16(bfrag[0], apkv[(18 * 2 + 0) * 64 + lane], acc, 0, 0, 0);
    acc = __builtin_amdgcn_mfma_f32_32x32x16_bf16(bfrag[1], apkv[(18 * 2 + 1) * 64 + lane], acc, 0, 0, 0);
    float bbv = bq[col];
#pragma unroll
    for (int g4 = 0; g4 < 4; ++g4) {
        short4_t sv;
#pragma unroll
        for (int j = 0; j < 4; ++j) {
            bf16 hb = __float2bfloat16(acc[g4 * 4 + j] + bbv);
            sv[j] = *reinterpret_cast<short*>(&hb);
        }
        *reinterpret_cast<short4_t*>(&lbuf[col][wvi * 32 + 8 * g4 + 4 * q]) = sv;
    }
    __syncthreads();
    int ch0 = tid >> 4, chk = tid & 15, ch1 = ch0 + 16;
    short8 v0 = *reinterpret_cast<const short8*>(&lbuf[ch0][chk * 8]);
    *reinterpret_cast<short8*>(xqb + (size_t)ch0 * S_ + pixw0 + chk * 8) = v0;
    short8 v1 = *reinterpret_cast<const short8*>(&lbuf[ch1][chk * 8]);
    *reinterpret_cast<short8*>(xqb + (size_t)ch1 * S_ + pixw0 + chk * 8) = v1;
}

// ---------------- fused K/V-conv + attention -----------------------------------
// Block = (batch, 512-px chunk). Flat-view structure: attention row tl consumes
// 288 CONSECUTIVE px of ONE shifted conv plane c' = (tl*288)>>16, sk0=(tl*288)&65535.
// Per tap p: MFMA K_p (32 planes x 800 px, halo 288) into LDS, serve rows with
// strip-start in [s0,s0+512) (skip straddlers), then write reg-held V_p and finish.
// x staged once (1314 px x 32ch bf16, conv3s-style granule swizzle). No HBM K/V.

// C-tile store: C[px][oc] (lane holds oc=col, 16 px). Masked (shift validity) +
// bias, granule-swizzled so strip reads are ~conflict-free.
__device__ __forceinline__ void tile_store(char* __restrict__ kvB, int T, int q, int oc,
                                           const f32x16& a, float bias,
                                           int dj, int hb_lo, int hb_hi)
{
#pragma unroll
    for (int G2 = 0; G2 < 4; ++G2) {
        int pxb = 32 * T + 8 * G2 + 4 * q;
        bool hbad = (pxb < hb_lo) || (pxb >= hb_hi);   // 256-aligned bounds: run-uniform
        short4_t sv;
#pragma unroll
        for (int j3 = 0; j3 < 4; ++j3) {
            int px = pxb + j3;
            bool wbad = (dj == 1 && (px & 255) == 255) || (dj == -1 && (px & 255) == 0);
            float val = (hbad || wbad) ? 0.f : (a[G2 * 4 + j3] + bias);
            bf16 h = __float2bfloat16(val);
            sv[j3] = *reinterpret_cast<short*>(&h);
        }
        *reinterpret_cast<short4_t*>(kvB + oc * 1616 +
            (((T << 2) + (G2 ^ ((oc >> 3) & 3))) << 4) + q * 8) = sv;
    }
}

#define CONV_TILE(T, VH, COND)                                                        \
    VH = (f32x16){};                                                                  \
    if (COND) {                                                                       \
        int xib = 32 * (T) + 257 + di * 256 + dj + col;                               \
        int swx = (xib ^ (xib >> 2)) & 3;                                             \
        short8 fa = *reinterpret_cast<const short8*>(&xs[xib * 4 + (q ^ swx)]);       \
        short8 fb = *reinterpret_cast<const short8*>(&xs[xib * 4 + ((2 + q) ^ swx)]); \
        f32x16 ka = (f32x16){};                                                       \
        ka = __builtin_amdgcn_mfma_f32_32x32x16_bf16(fa, apkv[(p * 2 + 0) * 64 + lane], ka, 0, 0, 0); \
        ka = __builtin_amdgcn_mfma_f32_32x32x16_bf16(fb, apkv[(p * 2 + 1) * 64 + lane], ka, 0, 0, 0); \
        VH = __builtin_amdgcn_mfma_f32_32x32x16_bf16(fa, apkv[((9 + p) * 2 + 0) * 64 + lane], VH, 0, 0, 0); \
        VH = __builtin_amdgcn_mfma_f32_32x32x16_bf16(fb, apkv[((9 + p) * 2 + 1) * 64 + lane], VH, 0, 0, 0); \
        tile_store(kvB, (T), q, col, ka, bK, dj, hb_lo, hb_hi);                       \
    }

#define V_TILE(T, VH, COND)                                                           \
    if (COND) tile_store(kvB, (T), q, col, VH, bV, dj, hb_lo, hb_hi);

__global__ __launch_bounds__(512, 2) void k_fused(
    const float* __restrict__ x,        // [4][32][65536] fp32
    const bf16* __restrict__ apk,       // packed weights [19][2][64][8]
    const float* __restrict__ bk, const float* __restrict__ bv,
    const bf16* __restrict__ xq,        // [4][32][65536] bf16 planar
    bf16* __restrict__ att)             // [4][2097152] flat bf16
{
    extern __shared__ char smem_raw[];
    uint4* xs  = reinterpret_cast<uint4*>(smem_raw);   // 1314 px * 4 granules = 84096 B
    char*  kvB = smem_raw + 84096;                     // 32 rows * 1616 B = 51712 B

    int bb = blockIdx.x >> 7;
    int s0 = (blockIdx.x & 127) << 9;

    int tid  = threadIdx.x;
    int lane = tid & 63;
    int wv   = tid >> 6;
    int col  = lane & 31;
    int q    = lane >> 5;

    const float* xb = x + (size_t)bb * (C_ * S_);

    // ---- stage x [s0-257, s0+1057) as bf16 NHWC granules, swizzled ----
    for (int i = tid; i < 5256; i += 512) {
        int xi = i >> 2, g = i & 3;
        int s = s0 - 257 + xi;
        short8 v;
        if ((unsigned)s < 65536u) {
#pragma unroll
            for (int j = 0; j < 8; ++j) {
                bf16 h = __float2bfloat16(xb[(size_t)(g * 8 + j) * S_ + s]);
                v[j] = *reinterpret_cast<short*>(&h);
            }
        } else {
#pragma unroll
            for (int j = 0; j < 8; ++j) v[j] = 0;
        }
        int sw = (xi ^ (xi >> 2)) & 3;
        *reinterpret_cast<short8*>(&xs[xi * 4 + (g ^ sw)]) = v;
    }
    __syncthreads();

    const short8* apkv = reinterpret_cast<const short8*>(apk);

    int grp  = tid >> 2, hh = tid & 3;
    int dp   = grp & 31;                 // plane d' within tap
    int krow = grp >> 5;                 // row-slot 0..3 (>=2 always invalid)
    size_t qbase = ((size_t)bb << 21);

#pragma unroll 1
    for (int p = 0; p < 9; ++p) {
        int di = p / 3 - 1, dj = p - (p / 3) * 3 - 1;
        int hb_lo = (di == -1) ? (256 - s0) : 0;
        int hb_hi = (di == 1) ? (65280 - s0) : 0x7FFFFFFF;
        float bK = bk[p * 32 + col];
        float bV = bv[p * 32 + col];

        f32x16 vh0, vh1, vh2, vh3;
        CONV_TILE(wv,      vh0, true)
        CONV_TILE(wv + 8,  vh1, true)
        CONV_TILE(wv + 16, vh2, true)
        CONV_TILE(wv + 24, vh3, (wv == 0))
        __syncthreads();

        // ---- scores + softmax for this tap's rows ----
        int plane_base = (p * 32 + dp) << 16;
        int tl  = (plane_base + s0 + 287) / 288 + krow;
        int sk0 = tl * 288 - plane_base;
        bool rowvalid = (sk0 < s0 + 512) && (sk0 <= 65248);
        float wgt[9];
        float inv_ = 0.f;
        if (rowvalid) {
            float qv[8];
            short8 qg = *reinterpret_cast<const short8*>(xq + qbase + ((size_t)tl << 5) + hh * 8);
#pragma unroll
            for (int j = 0; j < 8; ++j) qv[j] = b2f(qg[j]);
            float sc[9];
#pragma unroll
            for (int seg = 0; seg < 9; ++seg) {
                int pxr = sk0 - s0 + seg * 32 + hh * 8;
                int t = pxr >> 5, G2r = (pxr >> 3) & 3;
                short8 kg = *reinterpret_cast<const short8*>(
                    kvB + dp * 1616 + (((t << 2) + (G2r ^ ((dp >> 3) & 3))) << 4));
                float dot = 0.f;
#pragma unroll
                for (int j = 0; j < 8; ++j) dot += qv[j] * b2f(kg[j]);
                dot += __shfl_xor(dot, 1);
                dot += __shfl_xor(dot, 2);
                int rm = tl * 9 + seg;
                int pm = rm >> 16, sm = rm & 65535;
                int dim = pm / 3 - 1, djm = pm - (pm / 3) * 3 - 1;
                int hm = sm >> 8, wm = sm & 255;
                bool mval = ((unsigned)(hm + dim) < 256u) && ((unsigned)(wm + djm) < 256u);
                sc[seg] = mval ? dot * 0.125f : 0.f;
            }
            float mx = sc[0];
#pragma unroll
            for (int s2 = 1; s2 < 9; ++s2) mx = fmaxf(mx, sc[s2]);
            float sum = 0.f;
#pragma unroll
            for (int s2 = 0; s2 < 9; ++s2) { wgt[s2] = __expf(sc[s2] - mx); sum += wgt[s2]; }
            inv_ = 1.f / sum;
        }
        __syncthreads();

        // ---- V tiles (held in regs) overwrite K buffer ----
        V_TILE(wv,      vh0, true)
        V_TILE(wv + 8,  vh1, true)
        V_TILE(wv + 16, vh2, true)
        V_TILE(wv + 24, vh3, (wv == 0))
        __syncthreads();

        if (rowvalid) {
            float oacc[8] = {0.f, 0.f, 0.f, 0.f, 0.f, 0.f, 0.f, 0.f};
#pragma unroll
            for (int seg = 0; seg < 9; ++seg) {
                int pxr = sk0 - s0 + seg * 32 + hh * 8;
                int t = pxr >> 5, G2r = (pxr >> 3) & 3;
                short8 vg = *reinterpret_cast<const short8*>(
                    kvB + dp * 1616 + (((t << 2) + (G2r ^ ((dp >> 3) & 3))) << 4));
                float w_ = wgt[seg];
#pragma unroll
                for (int j = 0; j < 8; ++j) oacc[j] += w_ * b2f(vg[j]);
            }
            short8 sv;
#pragma unroll
            for (int j = 0; j < 8; ++j) {
                bf16 h = __float2bfloat16(oacc[j] * inv_);
                sv[j] = *reinterpret_cast<short*>(&h);
            }
            *reinterpret_cast<short8*>(att + qbase + ((size_t)tl << 5) + hh * 8) = sv;
        }
        __syncthreads();
    }
}

// ---------------- straddler rows: strip crosses a plane boundary ------------------
// 256 rows/batch: tl = g*2048 + ((2040+u)*1593 & 2047), g<32, u<8 (9^-1 mod 2048 = 1593).
// Recompute k/v directly from x in fp32 (more accurate than fused path; both pass).
__global__ __launch_bounds__(320) void k_strad(
    const float* __restrict__ x,
    const float* __restrict__ wk, const float* __restrict__ bk,
    const float* __restrict__ wv, const float* __restrict__ bv,
    const bf16* __restrict__ xq, bf16* __restrict__ att)
{
    __shared__ float kL[288], vL[288], qL[32], wgtL[10];
    int e = blockIdx.x;
    int b = e >> 8, i = e & 255;
    int g = i >> 3, u = i & 7;
    int tl = g * 2048 + (((2040 + u) * 1593) & 2047);
    int tid = threadIdx.x;

    if (tid < 288) {
        int f  = tl * 288 + tid;
        int cp = f >> 16;
        int sp = f & 65535;
        int tap = cp >> 5;
        int di = tap / 3 - 1, dj = tap - (tap / 3) * 3 - 1;
        int h = sp >> 8, w = sp & 255;
        bool valid = ((unsigned)(h + di) < 256u) && ((unsigned)(w + dj) < 256u);
        float kv_ = 0.f, vv_ = 0.f;
        if (valid) {
            int sx = sp + di * 256 + dj;
            const float* xp = x + (size_t)b * (C_ * S_) + sx;
            float ks = bk[cp], vs = bv[cp];
#pragma unroll
            for (int ic = 0; ic < 32; ++ic) {
                float xv_ = xp[(size_t)ic * S_];
                ks += wk[cp * 32 + ic] * xv_;
                vs += wv[cp * 32 + ic] * xv_;
            }
            kv_ = ks; vv_ = vs;
        }
        kL[tid] = kv_; vL[tid] = vv_;
    }
    if (tid < 32) {
        bf16 hv = xq[(size_t)b * (32 * S_) + (size_t)tl * 32 + tid];
        qL[tid] = b2f(*reinterpret_cast<short*>(&hv));
    }
    __syncthreads();
    if (tid < 9) {
        float dot = 0.f;
#pragma unroll
        for (int d = 0; d < 32; ++d) dot += kL[tid * 32 + d] * qL[d];
        int rm = tl * 9 + tid;
        int pm = rm >> 16, sm = rm & 65535;
        int dim = pm / 3 - 1, djm = pm - (pm / 3) * 3 - 1;
        int hm = sm >> 8, wm = sm & 255;
        bool mval = ((unsigned)(hm + dim) < 256u) && ((unsigned)(wm + djm) < 256u);
        wgtL[tid] = mval ? dot * 0.125f : 0.f;
    }
    __syncthreads();
    if (tid == 0) {
        float mx = wgtL[0];
#pragma unroll
        for (int s2 = 1; s2 < 9; ++s2) mx = fmaxf(mx, wgtL[s2]);
        float sum = 0.f;
#pragma unroll
        for (int s2 = 0; s2 < 9; ++s2) { wgtL[s2] = __expf(wgtL[s2] - mx); sum += wgtL[s2]; }
        wgtL[9] = 1.f / sum;
    }
    __syncthreads();
    if (tid < 32) {
        float acc = 0.f;
#pragma unroll
        for (int seg = 0; seg < 9; ++seg) acc += wgtL[seg] * vL[seg * 32 + tid];
        att[(size_t)b * 2097152 + (size_t)tl * 32 + tid] = __float2bfloat16(acc * wgtL[9]);
    }
}

// ---------------- K2: repack att (flat-identity planar bf16) -> tA (NHWC padded) ---
__global__ __launch_bounds__(256) void k_repack(
    const bf16* __restrict__ att, bf16* __restrict__ tA)
{
    int idx = blockIdx.x * 256 + threadIdx.x;   // [0, B*S*4)
    int icg = idx & 3;
    int ps  = idx >> 2;
    int b = ps >> 16;
    int s = ps & 65535;
    const bf16* src = att + (size_t)b * (32 * S_) + icg * 8 * S_ + s;
    short8 v;
#pragma unroll
    for (int j = 0; j < 8; ++j)
        v[j] = *reinterpret_cast<const short*>(src + (size_t)j * S_);
    int row = (s >> 8) + 1, colp = (s & 255) + 1;
    *reinterpret_cast<short8*>(tA + ((size_t)((b * PR + row) * PWN + colp)) * 32 + icg * 8) = v;
}

// ---------------- K4: 3x3 conv + ReLU via MFMA, one-shot LDS staging ----------------
template<int IC, int OC, bool NCHW_OUT>
__global__ __launch_bounds__(256) void k_conv3s(
    const bf16* __restrict__ in,    // NHWC bf16 padded [B][PR][PWN][IC]
    const bf16* __restrict__ apk,
    const float* __restrict__ bs,
    void* __restrict__ outv)
{
    constexpr int G    = IC / 8;
    constexpr int M    = OC / 32;
    constexpr int KPT  = IC / 16;
    constexpr int NK   = 9 * KPT;
    constexpr int NT   = 2;
    constexpr int ROWP = 66;
    constexpr int ROWG = ROWP * G;
    constexpr int TOTG = 6 * ROWG;

    __shared__ uint4 smem[TOTG];

    int wg   = blockIdx.x;
    int orig = (wg & 7) * 128 + (wg >> 3);
    int b   = orig >> 8;
    int rem = orig & 255;
    int h0  = (rem >> 2) << 2;
    int w0  = (rem & 3) * 64;

    int tid = threadIdx.x;

    {
        const uint4* src = reinterpret_cast<const uint4*>(in);
#pragma unroll
        for (int i = 0; i < (TOTG + 255) / 256; ++i) {
            int idx = tid + i * 256;
            if (idx < TOTG) {
                int dr = idx / ROWG;
                int r2 = idx - dr * ROWG;
                uint4 v = src[((size_t)(b * PR + h0 + dr) * PWN + w0) * G + r2];
                int px = r2 >> ((G == 4) ? 2 : 3);
                int sw = (G == 4) ? ((px ^ (px >> 2)) & 3) : (px & 7);
                smem[dr * ROWG + (r2 & ~(G - 1)) + ((r2 ^ sw) & (G - 1))] = v;
            }
        }
    }
    __syncthreads();

    int lane = tid & 63;
    int wid  = tid >> 6;
    int col  = lane & 31, q = lane >> 5;
    int h    = h0 + wid;

    const short8* apkv = reinterpret_cast<const short8*>(apk);

    f32x16 acc[NT][M];
#pragma unroll
    for (int nt = 0; nt < NT; ++nt)
#pragma unroll
        for (int mt = 0; mt < M; ++mt) acc[nt][mt] = (f32x16){};

#pragma unroll
    for (int tap = 0; tap < 9; ++tap) {
        int dr = tap / 3 + wid;
        int dj = tap % 3;
#pragma unroll
        for (int icq = 0; icq < KPT; ++icq) {
            short8 bfr[NT];
#pragma unroll
            for (int nt = 0; nt < NT; ++nt) {
                int px = nt * 32 + col + dj;
                int sw = (G == 4) ? ((px ^ (px >> 2)) & 3) : (px & 7);
                bfr[nt] = *reinterpret_cast<const short8*>(
                    &smem[dr * ROWG + px * G + ((icq * 2 + q) ^ sw)]);
            }
#pragma unroll
            for (int mt = 0; mt < M; ++mt) {
                short8 afr = apkv[(mt * NK + tap * KPT + icq) * 64 + lane];
#pragma unroll
                for (int nt = 0; nt < NT; ++nt)
                    acc[nt][mt] = __builtin_amdgcn_mfma_f32_32x32x16_bf16(
                        afr, bfr[nt], acc[nt][mt], 0, 0, 0);
            }
        }
    }

#pragma unroll
    for (int nt = 0; nt < NT; ++nt) {
        int wout = w0 + nt * 32 + col;
#pragma unroll
        for (int mt = 0; mt < M; ++mt) {
            if (NCHW_OUT) {
                float* out = (float*)outv;
#pragma unroll
                for (int r = 0; r < 16; ++r) {
                    int oc = mt * 32 + (r & 3) + 8 * (r >> 2) + 4 * q;
                    out[(size_t)((b * OC + oc) * H_ + h) * W_ + wout] =
                        fmaxf(acc[nt][mt][r] + bs[oc], 0.f);
                }
            } else {
                bf16* out = (bf16*)outv;
                size_t base = (size_t)((b * PR + h + 1) * PWN + wout + 1) * OC + mt * 32 + 4 * q;
#pragma unroll
                for (int g4 = 0; g4 < 4; ++g4) {
                    short4_t sv;
#pragma unroll
                    for (int r4 = 0; r4 < 4; ++r4) {
                        int oc = mt * 32 + 8 * g4 + 4 * q + r4;
                        bf16 hh = __float2bfloat16(fmaxf(acc[nt][mt][g4 * 4 + r4] + bs[oc], 0.f));
                        sv[r4] = *reinterpret_cast<short*>(&hh);
                    }
                    *reinterpret_cast<short4_t*>(out + base + 8 * g4) = sv;
                }
            }
        }
    }
}

extern "C" void kernel_launch(void* const* d_in, const int* in_sizes, int n_in,
                              void* d_out, int out_size, void* d_ws, size_t ws_size,
                              hipStream_t stream)
{
    const float* x  = (const float*)d_in[0];
    const float* wk = (const float*)d_in[1];
    const float* bk = (const float*)d_in[2];
    const float* wv = (const float*)d_in[3];
    const float* bv = (const float*)d_in[4];
    const float* wq = (const float*)d_in[5];
    const float* bq = (const float*)d_in[6];
    const float* w1 = (const float*)d_in[7];
    const float* b1 = (const float*)d_in[8];
    const float* w2 = (const float*)d_in[9];
    const float* b2 = (const float*)d_in[10];
    const float* w3 = (const float*)d_in[11];
    const float* b3 = (const float*)d_in[12];
    float* out = (float*)d_out;
    char* ws = (char*)d_ws;

    // ---- workspace layout (no xk/xv anymore; ~87 MB) ----
    bf16* xq   = (bf16*)(ws);                 // 16,777,216
    bf16* tA   = (bf16*)(ws + 16777216);      // 17,436,672
    bf16* t1   = (bf16*)(ws + 34213888);      // 17,436,672
    bf16* t2   = (bf16*)(ws + 51650560);      // 34,873,344
    bf16* apk0 = (bf16*)(ws + 86523904);      // 38,912
    bf16* apk1 = (bf16*)(ws + 86562816);      // 18,432
    bf16* apk2 = (bf16*)(ws + 86581248);      // 36,864
    bf16* apk3 = (bf16*)(ws + 86618112);      // 36,864  (end 86,654,976)
    bf16* attB = (bf16*)d_out;                // attention out scratch (dead until last conv)

    static bool attr_set = false;
    if (!attr_set) {
        hipFuncSetAttribute(reinterpret_cast<const void*>(k_fused),
                            hipFuncAttributeMaxDynamicSharedMemorySize, 135808);
        attr_set = true;
    }

    k_prep<<<516, 256, 0, stream>>>(wk, wv, wq, w1, w2, w3,
                                    apk0, apk1, apk2, apk3,
                                    (uint4*)tA, (uint4*)t1, (uint4*)t2);

    k_q<<<2048, 256, 0, stream>>>(x, apk0, bq, xq);

    k_fused<<<512, 512, 135808, stream>>>(x, apk0, bk, bv, xq, attB);

    k_strad<<<1024, 320, 0, stream>>>(x, wk, bk, wv, bv, xq, attB);

    k_repack<<<4096, 256, 0, stream>>>(attB, tA);

    k_conv3s<32, 32, false><<<1024, 256, 0, stream>>>(tA, apk1, b1, (void*)t1);
    k_conv3s<32, 64, false><<<1024, 256, 0, stream>>>(t1, apk2, b2, (void*)t2);
    k_conv3s<64, 32, true ><<<1024, 256, 0, stream>>>(t2, apk3, b3, (void*)out);
}

// Round 3
// 182.787 us; speedup vs baseline: 1.1154x; 1.0048x over previous
//
#include <hip/hip_runtime.h>
#include <hip/hip_bf16.h>

#define B_ 4
#define C_ 32
#define H_ 256
#define W_ 256
#define S_ 65536      // H*W
#define NP_ 9
#define OC_ 288       // C_*NP_
#define PR 258        // padded rows
#define PWN 264       // padded width stride (NHWC)

using bf16 = __hip_bfloat16;
typedef __attribute__((ext_vector_type(8)))  short  short8;
typedef __attribute__((ext_vector_type(4)))  short  short4_t;
typedef __attribute__((ext_vector_type(2)))  short  short2_t;
typedef __attribute__((ext_vector_type(16))) float  f32x16;

__device__ __forceinline__ float b2f(short s) {
    return __uint_as_float(((unsigned)(unsigned short)s) << 16);
}

// ---------------- prep bodies ----------------
template<int IC, int OC>
__device__ __forceinline__ void prepA_body(int fid, const float* __restrict__ w,
                                           bf16* __restrict__ apk)
{
    constexpr int NK = 9 * IC / 16;
    int tile = fid >> 9;
    int l = (fid >> 3) & 63;
    int j = fid & 7;
    int mt = tile / NK;
    int ks = tile - mt * NK;
    int q = l >> 5;
    int oc = mt * 32 + (l & 31);
    int k = ks * 16 + q * 8 + j;
    int tap = k / IC;
    int ic = k - tap * IC;
    apk[fid] = __float2bfloat16(w[((oc * IC + ic) * 3 + tap / 3) * 3 + tap % 3]);
}

template<int G>
__device__ __forceinline__ void zerob_body(int b, int p, uint4* __restrict__ buf)
{
    int gran;
    if (p < 2 * PWN * G) {
        int row = (p < PWN * G) ? 0 : 257;
        int rem = p % (PWN * G);
        gran = row * PWN * G + rem;
    } else {
        int p2 = p - 2 * PWN * G;
        int col = (p2 < 256 * G) ? 0 : 257;
        int rem = p2 % (256 * G);
        int r = rem / G + 1;
        int icg = rem - (rem / G) * G;
        gran = (r * PWN + col) * G + icg;
    }
    buf[(size_t)b * PR * PWN * G + gran] = uint4{0, 0, 0, 0};
}

// ---------------- K_prep: weight packs + border zeroing of tA/t1/t2 ----------------
__global__ __launch_bounds__(256) void k_prep(
    const float* __restrict__ wk, const float* __restrict__ wv,
    const float* __restrict__ wq,
    const float* __restrict__ w1, const float* __restrict__ w2,
    const float* __restrict__ w3,
    bf16* __restrict__ apk0, bf16* __restrict__ apk1,
    bf16* __restrict__ apk2, bf16* __restrict__ apk3,
    uint4* __restrict__ tA, uint4* __restrict__ t1, uint4* __restrict__ t2)
{
    int idx = blockIdx.x * 256 + threadIdx.x;
    if (idx < 19456) {
        int j    = idx & 7;
        int lane = (idx >> 3) & 63;
        int ks   = (idx >> 9) & 1;
        int mt   = idx >> 10;
        int oc = lane & 31;
        int ic = ks * 16 + (lane >> 5) * 8 + j;
        const float* w; int ocg;
        if (mt < 9)       { w = wk; ocg = mt * 32 + oc; }
        else if (mt < 18) { w = wv; ocg = (mt - 9) * 32 + oc; }
        else              { w = wq; ocg = oc; }
        apk0[idx] = __float2bfloat16(w[ocg * C_ + ic]);
    } else if (idx < 28672) {
        prepA_body<32, 32>(idx - 19456, w1, apk1);
    } else if (idx < 47104) {
        prepA_body<32, 64>(idx - 28672, w2, apk2);
    } else if (idx < 65536) {
        prepA_body<64, 32>(idx - 47104, w3, apk3);
    } else if (idx < 82176) {
        int i5 = idx - 65536;
        zerob_body<4>(i5 / 4160, i5 % 4160, tA);
    } else if (idx < 98816) {
        int i6 = idx - 82176;
        zerob_body<4>(i6 / 4160, i6 % 4160, t1);
    } else if (idx < 132096) {
        int i7 = idx - 98816;
        zerob_body<8>(i7 / 8320, i7 % 8320, t2);
    }
}

// ---------------- K_q: 1x1 Q-conv via MFMA, planar bf16 out, all 4 batches --------
__global__ __launch_bounds__(256) void k_q(
    const float* __restrict__ x, const bf16* __restrict__ apk,
    const float* __restrict__ bq, bf16* __restrict__ xq)
{
    __shared__ bf16 lbuf[32][140];
    int bh  = blockIdx.x >> 9;          // batch 0..3
    int blk = blockIdx.x & 511;
    int pixw0 = blk << 7;
    int tid  = threadIdx.x;
    int wvi  = tid >> 6;
    int lane = tid & 63;
    int col  = lane & 31, q = lane >> 5;
    int pix  = pixw0 + wvi * 32 + col;

    const float* xb = x + (size_t)bh * (C_ * S_);
    bf16* xqb = xq + (size_t)bh * (32 * S_);

    short8 bfrag[2];
#pragma unroll
    for (int kk = 0; kk < 2; ++kk)
#pragma unroll
        for (int j = 0; j < 8; ++j) {
            bf16 h = __float2bfloat16(xb[(size_t)(kk * 16 + q * 8 + j) * S_ + pix]);
            bfrag[kk][j] = *reinterpret_cast<short*>(&h);
        }

    const short8* apkv = reinterpret_cast<const short8*>(apk);
    f32x16 acc = {};
    acc = __builtin_amdgcn_mfma_f32_32x32x16_bf16(bfrag[0], apkv[(18 * 2 + 0) * 64 + lane], acc, 0, 0, 0);
    acc = __builtin_amdgcn_mfma_f32_32x32x16_bf16(bfrag[1], apkv[(18 * 2 + 1) * 64 + lane], acc, 0, 0, 0);
    float bbv = bq[col];
#pragma unroll
    for (int g4 = 0; g4 < 4; ++g4) {
        short4_t sv;
#pragma unroll
        for (int j = 0; j < 4; ++j) {
            bf16 hb = __float2bfloat16(acc[g4 * 4 + j] + bbv);
            sv[j] = *reinterpret_cast<short*>(&hb);
        }
        *reinterpret_cast<short4_t*>(&lbuf[col][wvi * 32 + 8 * g4 + 4 * q]) = sv;
    }
    __syncthreads();
    int ch0 = tid >> 4, chk = tid & 15, ch1 = ch0 + 16;
    short8 v0 = *reinterpret_cast<const short8*>(&lbuf[ch0][chk * 8]);
    *reinterpret_cast<short8*>(xqb + (size_t)ch0 * S_ + pixw0 + chk * 8) = v0;
    short8 v1 = *reinterpret_cast<const short8*>(&lbuf[ch1][chk * 8]);
    *reinterpret_cast<short8*>(xqb + (size_t)ch1 * S_ + pixw0 + chk * 8) = v1;
}

// ---------------- fused K/V-conv + attention -----------------------------------
// Block = (batch, 512-px chunk), 1024 threads (16 waves -> 4 waves/SIMD at
// 1 block/CU; grid 512 = exactly 2 rounds over 256 CUs). Per tap p: 16 waves
// MFMA the K tile (32 planes x 800 px) into LDS, 512 threads serve rows
// (8-way split: plane x krow{0,1} x hh x sh), V tiles from regs, PV. No HBM K/V.

__device__ __forceinline__ void tile_store(char* __restrict__ kvB, int T, int q, int oc,
                                           const f32x16& a, float bias,
                                           int dj, int hb_lo, int hb_hi)
{
#pragma unroll
    for (int G2 = 0; G2 < 4; ++G2) {
        int pxb = 32 * T + 8 * G2 + 4 * q;
        bool hbad = (pxb < hb_lo) || (pxb >= hb_hi);   // 256-aligned bounds: run-uniform
        short4_t sv;
#pragma unroll
        for (int j3 = 0; j3 < 4; ++j3) {
            int px = pxb + j3;
            bool wbad = (dj == 1 && (px & 255) == 255) || (dj == -1 && (px & 255) == 0);
            float val = (hbad || wbad) ? 0.f : (a[G2 * 4 + j3] + bias);
            bf16 h = __float2bfloat16(val);
            sv[j3] = *reinterpret_cast<short*>(&h);
        }
        *reinterpret_cast<short4_t*>(kvB + oc * 1616 +
            (((T << 2) + (G2 ^ ((oc >> 3) & 3))) << 4) + q * 8) = sv;
    }
}

#define CONV_TILE(T, VH, COND)                                                        \
    VH = (f32x16){};                                                                  \
    if (COND) {                                                                       \
        int xib = 32 * (T) + 257 + di * 256 + dj + col;                               \
        int swx = (xib ^ (xib >> 2)) & 3;                                             \
        short8 fa = *reinterpret_cast<const short8*>(&xs[xib * 4 + (q ^ swx)]);       \
        short8 fb = *reinterpret_cast<const short8*>(&xs[xib * 4 + ((2 + q) ^ swx)]); \
        f32x16 ka = (f32x16){};                                                       \
        ka = __builtin_amdgcn_mfma_f32_32x32x16_bf16(fa, apkv[(p * 2 + 0) * 64 + lane], ka, 0, 0, 0); \
        ka = __builtin_amdgcn_mfma_f32_32x32x16_bf16(fb, apkv[(p * 2 + 1) * 64 + lane], ka, 0, 0, 0); \
        VH = __builtin_amdgcn_mfma_f32_32x32x16_bf16(fa, apkv[((9 + p) * 2 + 0) * 64 + lane], VH, 0, 0, 0); \
        VH = __builtin_amdgcn_mfma_f32_32x32x16_bf16(fb, apkv[((9 + p) * 2 + 1) * 64 + lane], VH, 0, 0, 0); \
        tile_store(kvB, (T), q, col, ka, bK, dj, hb_lo, hb_hi);                       \
    }

#define V_TILE(T, VH, COND)                                                           \
    if (COND) tile_store(kvB, (T), q, col, VH, bV, dj, hb_lo, hb_hi);

__global__ __launch_bounds__(1024, 4) void k_fused(
    const float* __restrict__ x,        // [4][32][65536] fp32
    const bf16* __restrict__ apk,       // packed weights [19][2][64][8]
    const float* __restrict__ bk, const float* __restrict__ bv,
    const bf16* __restrict__ xq,        // [4][32][65536] bf16 planar
    bf16* __restrict__ att)             // [4][2097152] flat bf16
{
    extern __shared__ char smem_raw[];
    uint4* xs  = reinterpret_cast<uint4*>(smem_raw);   // 1314 px * 4 granules = 84096 B
    char*  kvB = smem_raw + 84096;                     // 32 rows * 1616 B = 51712 B

    int bb = blockIdx.x >> 7;
    int s0 = (blockIdx.x & 127) << 9;

    int tid  = threadIdx.x;
    int lane = tid & 63;
    int wv   = tid >> 6;                // 0..15
    int col  = lane & 31;
    int q    = lane >> 5;

    const float* xb = x + (size_t)bb * (C_ * S_);

    // ---- stage x [s0-257, s0+1057) as bf16 NHWC granules, swizzled ----
    for (int i = tid; i < 5256; i += 1024) {
        int xi = i >> 2, g = i & 3;
        int s = s0 - 257 + xi;
        short8 v;
        if ((unsigned)s < 65536u) {
#pragma unroll
            for (int j = 0; j < 8; ++j) {
                bf16 h = __float2bfloat16(xb[(size_t)(g * 8 + j) * S_ + s]);
                v[j] = *reinterpret_cast<short*>(&h);
            }
        } else {
#pragma unroll
            for (int j = 0; j < 8; ++j) v[j] = 0;
        }
        int sw = (xi ^ (xi >> 2)) & 3;
        *reinterpret_cast<short8*>(&xs[xi * 4 + (g ^ sw)]) = v;
    }

    const short8* apkv = reinterpret_cast<const short8*>(apk);

    // attention thread map: tid<512, 8 threads per (plane, krow) slot
    int grp  = tid >> 3, sub = tid & 7;
    int dp   = grp & 31;                 // plane d' within tap
    int krow = (grp >> 5) & 1;           // row-slot 0..1 (max 2 strips start in 512px)
    int hh   = sub >> 1;                 // d-octet 0..3
    int sh   = sub & 1;                  // quad within octet
    bool athr = tid < 512;
    size_t qbase = ((size_t)bb << 21);

    __syncthreads();

#pragma unroll 1
    for (int p = 0; p < 9; ++p) {
        int di = p / 3 - 1, dj = p - (p / 3) * 3 - 1;
        int hb_lo = (di == -1) ? (256 - s0) : 0;
        int hb_hi = (di == 1) ? (65280 - s0) : 0x7FFFFFFF;
        float bK = bk[p * 32 + col];
        float bV = bv[p * 32 + col];

        // ---- row mapping + early q load (hides under MFMA + barrier) ----
        int tl = 0, sk0 = 0; bool rv = false;
        short4_t qg = {};
        if (athr) {
            int plane_base = (p * 32 + dp) << 16;
            tl  = (plane_base + s0 + 287) / 288 + krow;
            sk0 = tl * 288 - plane_base;
            rv  = (sk0 < s0 + 512) && (sk0 <= 65248);
            if (rv) qg = *reinterpret_cast<const short4_t*>(
                         xq + qbase + ((size_t)tl << 5) + hh * 8 + sh * 4);
        }

        f32x16 vh0, vh1;
        CONV_TILE(wv,      vh0, true)
        CONV_TILE(wv + 16, vh1, (wv < 9))
        __syncthreads();

        // ---- scores + softmax for this tap's rows ----
        float wgt[9];
        float inv_ = 0.f;
        if (rv) {
            float qv[4];
#pragma unroll
            for (int j = 0; j < 4; ++j) qv[j] = b2f(qg[j]);
            int swz = (dp >> 3) & 3;
            int t0  = (sk0 - s0) >> 5;
            float sc[9];
#pragma unroll
            for (int seg = 0; seg < 9; ++seg) {
                short4_t kg = *reinterpret_cast<const short4_t*>(
                    kvB + dp * 1616 + ((((t0 + seg) << 2) + (hh ^ swz)) << 4) + sh * 8);
                float dot = 0.f;
#pragma unroll
                for (int j = 0; j < 4; ++j) dot += qv[j] * b2f(kg[j]);
                dot += __shfl_xor(dot, 1);
                dot += __shfl_xor(dot, 2);
                dot += __shfl_xor(dot, 4);
                int rm = tl * 9 + seg;
                int pm = rm >> 16, sm = rm & 65535;
                int dim = pm / 3 - 1, djm = pm - (pm / 3) * 3 - 1;
                int hm = sm >> 8, wm = sm & 255;
                bool mval = ((unsigned)(hm + dim) < 256u) && ((unsigned)(wm + djm) < 256u);
                sc[seg] = mval ? dot * 0.125f : 0.f;
            }
            float mx = sc[0];
#pragma unroll
            for (int s2 = 1; s2 < 9; ++s2) mx = fmaxf(mx, sc[s2]);
            float sum = 0.f;
#pragma unroll
            for (int s2 = 0; s2 < 9; ++s2) { wgt[s2] = __expf(sc[s2] - mx); sum += wgt[s2]; }
            inv_ = 1.f / sum;
        }
        __syncthreads();

        // ---- V tiles (held in regs) overwrite K buffer ----
        V_TILE(wv,      vh0, true)
        V_TILE(wv + 16, vh1, (wv < 9))
        __syncthreads();

        if (rv) {
            int swz = (dp >> 3) & 3;
            int t0  = (sk0 - s0) >> 5;
            float oacc[4] = {0.f, 0.f, 0.f, 0.f};
#pragma unroll
            for (int seg = 0; seg < 9; ++seg) {
                short4_t vg = *reinterpret_cast<const short4_t*>(
                    kvB + dp * 1616 + ((((t0 + seg) << 2) + (hh ^ swz)) << 4) + sh * 8);
                float w_ = wgt[seg];
#pragma unroll
                for (int j = 0; j < 4; ++j) oacc[j] += w_ * b2f(vg[j]);
            }
            short4_t sv;
#pragma unroll
            for (int j = 0; j < 4; ++j) {
                bf16 h = __float2bfloat16(oacc[j] * inv_);
                sv[j] = *reinterpret_cast<short*>(&h);
            }
            *reinterpret_cast<short4_t*>(att + qbase + ((size_t)tl << 5) + hh * 8 + sh * 4) = sv;
        }
        __syncthreads();
    }
}

// ---------------- straddler rows: strip crosses a plane boundary ------------------
__global__ __launch_bounds__(320) void k_strad(
    const float* __restrict__ x,
    const float* __restrict__ wk, const float* __restrict__ bk,
    const float* __restrict__ wv, const float* __restrict__ bv,
    const bf16* __restrict__ xq, bf16* __restrict__ att)
{
    __shared__ float kL[288], vL[288], qL[32], wgtL[10];
    int e = blockIdx.x;
    int b = e >> 8, i = e & 255;
    int g = i >> 3, u = i & 7;
    int tl = g * 2048 + (((2040 + u) * 1593) & 2047);
    int tid = threadIdx.x;

    if (tid < 288) {
        int f  = tl * 288 + tid;
        int cp = f >> 16;
        int sp = f & 65535;
        int tap = cp >> 5;
        int di = tap / 3 - 1, dj = tap - (tap / 3) * 3 - 1;
        int h = sp >> 8, w = sp & 255;
        bool valid = ((unsigned)(h + di) < 256u) && ((unsigned)(w + dj) < 256u);
        float kv_ = 0.f, vv_ = 0.f;
        if (valid) {
            int sx = sp + di * 256 + dj;
            const float* xp = x + (size_t)b * (C_ * S_) + sx;
            float ks = bk[cp], vs = bv[cp];
#pragma unroll
            for (int ic = 0; ic < 32; ++ic) {
                float xv_ = xp[(size_t)ic * S_];
                ks += wk[cp * 32 + ic] * xv_;
                vs += wv[cp * 32 + ic] * xv_;
            }
            kv_ = ks; vv_ = vs;
        }
        kL[tid] = kv_; vL[tid] = vv_;
    }
    if (tid < 32) {
        bf16 hv = xq[(size_t)b * (32 * S_) + (size_t)tl * 32 + tid];
        qL[tid] = b2f(*reinterpret_cast<short*>(&hv));
    }
    __syncthreads();
    if (tid < 9) {
        float dot = 0.f;
#pragma unroll
        for (int d = 0; d < 32; ++d) dot += kL[tid * 32 + d] * qL[d];
        int rm = tl * 9 + tid;
        int pm = rm >> 16, sm = rm & 65535;
        int dim = pm / 3 - 1, djm = pm - (pm / 3) * 3 - 1;
        int hm = sm >> 8, wm = sm & 255;
        bool mval = ((unsigned)(hm + dim) < 256u) && ((unsigned)(wm + djm) < 256u);
        wgtL[tid] = mval ? dot * 0.125f : 0.f;
    }
    __syncthreads();
    if (tid == 0) {
        float mx = wgtL[0];
#pragma unroll
        for (int s2 = 1; s2 < 9; ++s2) mx = fmaxf(mx, wgtL[s2]);
        float sum = 0.f;
#pragma unroll
        for (int s2 = 0; s2 < 9; ++s2) { wgtL[s2] = __expf(wgtL[s2] - mx); sum += wgtL[s2]; }
        wgtL[9] = 1.f / sum;
    }
    __syncthreads();
    if (tid < 32) {
        float acc = 0.f;
#pragma unroll
        for (int seg = 0; seg < 9; ++seg) acc += wgtL[seg] * vL[seg * 32 + tid];
        att[(size_t)b * 2097152 + (size_t)tl * 32 + tid] = __float2bfloat16(acc * wgtL[9]);
    }
}

// ---------------- K2: repack att (flat-identity planar bf16) -> tA (NHWC padded) ---
__global__ __launch_bounds__(256) void k_repack(
    const bf16* __restrict__ att, bf16* __restrict__ tA)
{
    int idx = blockIdx.x * 256 + threadIdx.x;   // [0, B*S*4)
    int icg = idx & 3;
    int ps  = idx >> 2;
    int b = ps >> 16;
    int s = ps & 65535;
    const bf16* src = att + (size_t)b * (32 * S_) + icg * 8 * S_ + s;
    short8 v;
#pragma unroll
    for (int j = 0; j < 8; ++j)
        v[j] = *reinterpret_cast<const short*>(src + (size_t)j * S_);
    int row = (s >> 8) + 1, colp = (s & 255) + 1;
    *reinterpret_cast<short8*>(tA + ((size_t)((b * PR + row) * PWN + colp)) * 32 + icg * 8) = v;
}

// ---------------- K4: 3x3 conv + ReLU via MFMA, one-shot LDS staging ----------------
template<int IC, int OC, bool NCHW_OUT>
__global__ __launch_bounds__(256) void k_conv3s(
    const bf16* __restrict__ in,    // NHWC bf16 padded [B][PR][PWN][IC]
    const bf16* __restrict__ apk,
    const float* __restrict__ bs,
    void* __restrict__ outv)
{
    constexpr int G    = IC / 8;
    constexpr int M    = OC / 32;
    constexpr int KPT  = IC / 16;
    constexpr int NK   = 9 * KPT;
    constexpr int NT   = 2;
    constexpr int ROWP = 66;
    constexpr int ROWG = ROWP * G;
    constexpr int TOTG = 6 * ROWG;

    __shared__ uint4 smem[TOTG];

    int wg   = blockIdx.x;
    int orig = (wg & 7) * 128 + (wg >> 3);
    int b   = orig >> 8;
    int rem = orig & 255;
    int h0  = (rem >> 2) << 2;
    int w0  = (rem & 3) * 64;

    int tid = threadIdx.x;

    {
        const uint4* src = reinterpret_cast<const uint4*>(in);
#pragma unroll
        for (int i = 0; i < (TOTG + 255) / 256; ++i) {
            int idx = tid + i * 256;
            if (idx < TOTG) {
                int dr = idx / ROWG;
                int r2 = idx - dr * ROWG;
                uint4 v = src[((size_t)(b * PR + h0 + dr) * PWN + w0) * G + r2];
                int px = r2 >> ((G == 4) ? 2 : 3);
                int sw = (G == 4) ? ((px ^ (px >> 2)) & 3) : (px & 7);
                smem[dr * ROWG + (r2 & ~(G - 1)) + ((r2 ^ sw) & (G - 1))] = v;
            }
        }
    }
    __syncthreads();

    int lane = tid & 63;
    int wid  = tid >> 6;
    int col  = lane & 31, q = lane >> 5;
    int h    = h0 + wid;

    const short8* apkv = reinterpret_cast<const short8*>(apk);

    f32x16 acc[NT][M];
#pragma unroll
    for (int nt = 0; nt < NT; ++nt)
#pragma unroll
        for (int mt = 0; mt < M; ++mt) acc[nt][mt] = (f32x16){};

#pragma unroll
    for (int tap = 0; tap < 9; ++tap) {
        int dr = tap / 3 + wid;
        int dj = tap % 3;
#pragma unroll
        for (int icq = 0; icq < KPT; ++icq) {
            short8 bfr[NT];
#pragma unroll
            for (int nt = 0; nt < NT; ++nt) {
                int px = nt * 32 + col + dj;
                int sw = (G == 4) ? ((px ^ (px >> 2)) & 3) : (px & 7);
                bfr[nt] = *reinterpret_cast<const short8*>(
                    &smem[dr * ROWG + px * G + ((icq * 2 + q) ^ sw)]);
            }
#pragma unroll
            for (int mt = 0; mt < M; ++mt) {
                short8 afr = apkv[(mt * NK + tap * KPT + icq) * 64 + lane];
#pragma unroll
                for (int nt = 0; nt < NT; ++nt)
                    acc[nt][mt] = __builtin_amdgcn_mfma_f32_32x32x16_bf16(
                        afr, bfr[nt], acc[nt][mt], 0, 0, 0);
            }
        }
    }

#pragma unroll
    for (int nt = 0; nt < NT; ++nt) {
        int wout = w0 + nt * 32 + col;
#pragma unroll
        for (int mt = 0; mt < M; ++mt) {
            if (NCHW_OUT) {
                float* out = (float*)outv;
#pragma unroll
                for (int r = 0; r < 16; ++r) {
                    int oc = mt * 32 + (r & 3) + 8 * (r >> 2) + 4 * q;
                    out[(size_t)((b * OC + oc) * H_ + h) * W_ + wout] =
                        fmaxf(acc[nt][mt][r] + bs[oc], 0.f);
                }
            } else {
                bf16* out = (bf16*)outv;
                size_t base = (size_t)((b * PR + h + 1) * PWN + wout + 1) * OC + mt * 32 + 4 * q;
#pragma unroll
                for (int g4 = 0; g4 < 4; ++g4) {
                    short4_t sv;
#pragma unroll
                    for (int r4 = 0; r4 < 4; ++r4) {
                        int oc = mt * 32 + 8 * g4 + 4 * q + r4;
                        bf16 hh = __float2bfloat16(fmaxf(acc[nt][mt][g4 * 4 + r4] + bs[oc], 0.f));
                        sv[r4] = *reinterpret_cast<short*>(&hh);
                    }
                    *reinterpret_cast<short4_t*>(out + base + 8 * g4) = sv;
                }
            }
        }
    }
}

extern "C" void kernel_launch(void* const* d_in, const int* in_sizes, int n_in,
                              void* d_out, int out_size, void* d_ws, size_t ws_size,
                              hipStream_t stream)
{
    const float* x  = (const float*)d_in[0];
    const float* wk = (const float*)d_in[1];
    const float* bk = (const float*)d_in[2];
    const float* wv = (const float*)d_in[3];
    const float* bv = (const float*)d_in[4];
    const float* wq = (const float*)d_in[5];
    const float* bq = (const float*)d_in[6];
    const float* w1 = (const float*)d_in[7];
    const float* b1 = (const float*)d_in[8];
    const float* w2 = (const float*)d_in[9];
    const float* b2 = (const float*)d_in[10];
    const float* w3 = (const float*)d_in[11];
    const float* b3 = (const float*)d_in[12];
    float* out = (float*)d_out;
    char* ws = (char*)d_ws;

    // ---- workspace layout (~87 MB) ----
    bf16* xq   = (bf16*)(ws);                 // 16,777,216
    bf16* tA   = (bf16*)(ws + 16777216);      // 17,436,672
    bf16* t1   = (bf16*)(ws + 34213888);      // 17,436,672
    bf16* t2   = (bf16*)(ws + 51650560);      // 34,873,344
    bf16* apk0 = (bf16*)(ws + 86523904);      // 38,912
    bf16* apk1 = (bf16*)(ws + 86562816);      // 18,432
    bf16* apk2 = (bf16*)(ws + 86581248);      // 36,864
    bf16* apk3 = (bf16*)(ws + 86618112);      // 36,864  (end 86,654,976)
    bf16* attB = (bf16*)d_out;                // attention out scratch (dead until last conv)

    static bool attr_set = false;
    if (!attr_set) {
        hipFuncSetAttribute(reinterpret_cast<const void*>(k_fused),
                            hipFuncAttributeMaxDynamicSharedMemorySize, 135808);
        attr_set = true;
    }

    k_prep<<<516, 256, 0, stream>>>(wk, wv, wq, w1, w2, w3,
                                    apk0, apk1, apk2, apk3,
                                    (uint4*)tA, (uint4*)t1, (uint4*)t2);

    k_q<<<2048, 256, 0, stream>>>(x, apk0, bq, xq);

    k_fused<<<512, 1024, 135808, stream>>>(x, apk0, bk, bv, xq, attB);

    k_strad<<<1024, 320, 0, stream>>>(x, wk, bk, wv, bv, xq, attB);

    k_repack<<<4096, 256, 0, stream>>>(attB, tA);

    k_conv3s<32, 32, false><<<1024, 256, 0, stream>>>(tA, apk1, b1, (void*)t1);
    k_conv3s<32, 64, false><<<1024, 256, 0, stream>>>(t1, apk2, b2, (void*)t2);
    k_conv3s<64, 32, true ><<<1024, 256, 0, stream>>>(t2, apk3, b3, (void*)out);
}